// Round 12
// baseline (86.890 us; speedup 1.0000x reference)
//
#include <hip/hip_runtime.h>

typedef short  bf16x8 __attribute__((ext_vector_type(8)));

#define JS      10           // j-splits (grid.y)
#define STREAMS (JS * 4)     // 40 wave-streams per i-tile (stride in j-tiles)
#define TI      64           // i-points per block (2 MFMA groups)
#define DEPTH   4            // prefetch depth (buffers X/Y/Z/W)

__device__ __forceinline__ unsigned short f2bf(float x) {
    unsigned u = __builtin_bit_cast(unsigned, x);
    u += 0x7FFF + ((u >> 16) & 1);          // RNE
    return (unsigned short)(u >> 16);
}
__device__ __forceinline__ float bf2f(unsigned short h) {
    unsigned u = ((unsigned)h) << 16;
    return __builtin_bit_cast(float, u);
}

// ---- pack padding points into MFMA-A planes + zero the output ----
// Row j (K=16 bf16): k0-2 qh | k3-5 ql | k6-8 qh | k9-11 ql | k12-13 negc h/l | 0,0
// plane0 = k0-7 (lanes 0-31), plane1 = k8-15 (lanes 32-63).
__global__ __launch_bounds__(256) void dens_pack_kernel(
    const float* __restrict__ pad, uint4* __restrict__ ws,
    int* __restrict__ out, int M, int mtot, int N)
{
    const int j = blockIdx.x * 256 + threadIdx.x;
    if (j < N) out[j] = 0;                      // fold output zeroing here
    if (j >= mtot) return;

    float qx = 0.f, qy = 0.f, qz = 0.f;
    float negc = -1.0e6f;                       // padded rows: sign -1 cancels +1 baseline
    if (j < M) {
        qx = pad[3 * j]; qy = pad[3 * j + 1]; qz = pad[3 * j + 2];
        negc = 0.125f - 0.5f * (qx * qx + qy * qy + qz * qz);   // (r^2 - |q|^2)/2
    }
    const unsigned short xh = f2bf(qx), yh = f2bf(qy), zh = f2bf(qz);
    const unsigned short xl = f2bf(qx - bf2f(xh));
    const unsigned short yl = f2bf(qy - bf2f(yh));
    const unsigned short zl = f2bf(qz - bf2f(zh));
    const unsigned short ch = f2bf(negc);
    const unsigned short cl = f2bf(negc - bf2f(ch));

    uint4 p0, p1;
    p0.x = (unsigned)xh | ((unsigned)yh << 16);   // k0,k1
    p0.y = (unsigned)zh | ((unsigned)xl << 16);   // k2,k3
    p0.z = (unsigned)yl | ((unsigned)zl << 16);   // k4,k5
    p0.w = (unsigned)xh | ((unsigned)yh << 16);   // k6,k7
    p1.x = (unsigned)zh | ((unsigned)xl << 16);   // k8,k9
    p1.y = (unsigned)yl | ((unsigned)zl << 16);   // k10,k11
    p1.z = (unsigned)ch | ((unsigned)cl << 16);   // k12,k13
    p1.w = 0;                                     // k14,k15
    ws[j]        = p0;                            // plane0
    ws[mtot + j] = p1;                            // plane1
}

__device__ __forceinline__ void make_bfrag(const float* __restrict__ pc,
                                           int i, int N, int half,
                                           bf16x8& B, float& nha)
{
    float px = 0.f, py = 0.f, pz = 0.f;
    float ha = 3.0e38f;                          // i-pad: s < 0 always (discarded anyway)
    if (i < N) {
        px = pc[3 * i]; py = pc[3 * i + 1]; pz = pc[3 * i + 2];
        ha = 0.5f * (px * px + py * py + pz * pz);   // |p|^2/2, fp32
    }
    nha = -ha;                                   // folded into MFMA C operand
    const short xh = (short)f2bf(px), yh = (short)f2bf(py), zh = (short)f2bf(pz);
    const short xl = (short)f2bf(px - bf2f((unsigned short)xh));
    const short yl = (short)f2bf(py - bf2f((unsigned short)yh));
    const short zl = (short)f2bf(pz - bf2f((unsigned short)zh));
    const short ONE = (short)0x3F80;
    const bf16x8 B0 = {xh, yh, zh, xh, yh, zh, xl, yl};   // k0-7
    const bf16x8 B1 = {zl, xl, yl, zl, ONE, ONE, 0, 0};   // k8-15
    B = half ? B1 : B0;
}

// consume one 16-elem D group: 16 in-place sign-extracts (full-rate VOP2)
// + 8 v_add3 into two alternating counters (full-rate VOP3, dep distance 4cyc).
// No SGPR-writing VALU (v_cmp/v_addc measured half-rate on CDNA4: R6/R9/R10).
#define CONS(R0,R1,R2,R3,R4,R5,R6,R7,R8,R9,RA,RB,RC,RD,RE,RF, CA, CB) \
    "v_ashrrev_i32 " R0 ", 31, " R0 "\n\t" \
    "v_ashrrev_i32 " R1 ", 31, " R1 "\n\t" \
    "v_ashrrev_i32 " R2 ", 31, " R2 "\n\t" \
    "v_ashrrev_i32 " R3 ", 31, " R3 "\n\t" \
    "v_ashrrev_i32 " R4 ", 31, " R4 "\n\t" \
    "v_ashrrev_i32 " R5 ", 31, " R5 "\n\t" \
    "v_ashrrev_i32 " R6 ", 31, " R6 "\n\t" \
    "v_ashrrev_i32 " R7 ", 31, " R7 "\n\t" \
    "v_ashrrev_i32 " R8 ", 31, " R8 "\n\t" \
    "v_ashrrev_i32 " R9 ", 31, " R9 "\n\t" \
    "v_ashrrev_i32 " RA ", 31, " RA "\n\t" \
    "v_ashrrev_i32 " RB ", 31, " RB "\n\t" \
    "v_ashrrev_i32 " RC ", 31, " RC "\n\t" \
    "v_ashrrev_i32 " RD ", 31, " RD "\n\t" \
    "v_ashrrev_i32 " RE ", 31, " RE "\n\t" \
    "v_ashrrev_i32 " RF ", 31, " RF "\n\t" \
    "v_add3_u32 " CA ", " R0 ", " R1 ", " CA "\n\t" \
    "v_add3_u32 " CB ", " R2 ", " R3 ", " CB "\n\t" \
    "v_add3_u32 " CA ", " R4 ", " R5 ", " CA "\n\t" \
    "v_add3_u32 " CB ", " R6 ", " R7 ", " CB "\n\t" \
    "v_add3_u32 " CA ", " R8 ", " R9 ", " CA "\n\t" \
    "v_add3_u32 " CB ", " RA ", " RB ", " CB "\n\t" \
    "v_add3_u32 " CA ", " RC ", " RD ", " CA "\n\t" \
    "v_add3_u32 " CB ", " RE ", " RF ", " CB "\n\t"

#define CONS_D0(CA, CB) \
    CONS("v32","v33","v34","v35","v36","v37","v38","v39", \
         "v40","v41","v42","v43","v44","v45","v46","v47", CA, CB)
#define CONS_D1(CA, CB) \
    CONS("v48","v49","v50","v51","v52","v53","v54","v55", \
         "v56","v57","v58","v59","v60","v61","v62","v63", CA, CB)

// One visit on A-buffer AR: wait only the OLDEST of 4 in-flight loads
// (issued 4 visit-bodies upstream ~ >1500 wall cyc: covers HBM miss), 2 MFMAs
// with C = -ha banks ("within" == sign 0), reload AR via the single marching
// address v[112:113], consume both D groups. s_nop 7/2 = proven MFMA->VALU gap.
#define VISIT(AR) \
    "s_waitcnt vmcnt(3)\n\t" \
    "v_mfma_f32_32x32x16_bf16 v[32:47], " AR ", %5, v[64:79]\n\t" \
    "v_mfma_f32_32x32x16_bf16 v[48:63], " AR ", %6, v[80:95]\n\t" \
    "global_load_dwordx4 " AR ", v[112:113], off\n\t" \
    "v_add_co_u32 v112, vcc, 0x5000, v112\n\t" \
    "v_addc_co_u32 v113, vcc, 0, v113, vcc\n\t" \
    "s_nop 7\n\t" \
    "s_nop 2\n\t" \
    CONS_D0("%0", "%1") \
    CONS_D1("%2", "%3")

// grid (313 x 10), 256 thr. 64-wide i-tile; 40 wave-streams stride j-tiles.
// Physical map: d0=v[32:47] d1=v[48:63] C0=v[64:79] C1=v[80:95]
//   X=v[96:99] Y=v[100:103] Z=v[104:107] W=v[108:111] addr=v[112:113].
// 20 visits/stream, 4-deep rotation, 5 loop iterations.
__global__ __launch_bounds__(256, 4) void dens_mfma_kernel(
    const float* __restrict__ pc,     // [N,3] pointcloud
    const char*  __restrict__ wsA,    // packed A planes ((visits+DEPTH)*STREAMS tiles)
    int* __restrict__ out,            // [N] counts (pre-zeroed)
    int N, int iters, int p1off, int visits)
{
    const int lane = threadIdx.x & 63;
    const int w    = threadIdx.x >> 6;   // wave 0..3
    const int n    = lane & 31;          // output col within 32-tile = i
    const int half = lane >> 5;          // k-chunk 0/1

    const int ibase = blockIdx.x * TI;
    bf16x8 B0, B1; float nha0, nha1;
    make_bfrag(pc, ibase + n,      N, half, B0, nha0);
    make_bfrag(pc, ibase + 32 + n, N, half, B1, nha1);

    const int stream = blockIdx.y * 4 + w;          // 0..39
    const unsigned long long ax =
        (unsigned long long)(wsA + (half ? p1off : 0) + n * 16 + (size_t)stream * 512);
    const unsigned xlo = (unsigned)ax, xhi = (unsigned)(ax >> 32);

    int it = iters;
    int c0a = 0, c0b = 0, c1a = 0, c1b = 0;

    asm volatile(
        // ---- preamble: marching addr, C banks = -ha splat, DEPTH prefetches ----
        "v_mov_b32 v112, %7\n\t"
        "v_mov_b32 v113, %8\n\t"
        "v_mov_b32 v64, %9\n\t"  "v_mov_b32 v65, %9\n\t"
        "v_mov_b32 v66, %9\n\t"  "v_mov_b32 v67, %9\n\t"
        "v_mov_b32 v68, %9\n\t"  "v_mov_b32 v69, %9\n\t"
        "v_mov_b32 v70, %9\n\t"  "v_mov_b32 v71, %9\n\t"
        "v_mov_b32 v72, %9\n\t"  "v_mov_b32 v73, %9\n\t"
        "v_mov_b32 v74, %9\n\t"  "v_mov_b32 v75, %9\n\t"
        "v_mov_b32 v76, %9\n\t"  "v_mov_b32 v77, %9\n\t"
        "v_mov_b32 v78, %9\n\t"  "v_mov_b32 v79, %9\n\t"
        "v_mov_b32 v80, %10\n\t" "v_mov_b32 v81, %10\n\t"
        "v_mov_b32 v82, %10\n\t" "v_mov_b32 v83, %10\n\t"
        "v_mov_b32 v84, %10\n\t" "v_mov_b32 v85, %10\n\t"
        "v_mov_b32 v86, %10\n\t" "v_mov_b32 v87, %10\n\t"
        "v_mov_b32 v88, %10\n\t" "v_mov_b32 v89, %10\n\t"
        "v_mov_b32 v90, %10\n\t" "v_mov_b32 v91, %10\n\t"
        "v_mov_b32 v92, %10\n\t" "v_mov_b32 v93, %10\n\t"
        "v_mov_b32 v94, %10\n\t" "v_mov_b32 v95, %10\n\t"
        "global_load_dwordx4 v[96:99], v[112:113], off\n\t"
        "v_add_co_u32 v112, vcc, 0x5000, v112\n\t"
        "v_addc_co_u32 v113, vcc, 0, v113, vcc\n\t"
        "global_load_dwordx4 v[100:103], v[112:113], off\n\t"
        "v_add_co_u32 v112, vcc, 0x5000, v112\n\t"
        "v_addc_co_u32 v113, vcc, 0, v113, vcc\n\t"
        "global_load_dwordx4 v[104:107], v[112:113], off\n\t"
        "v_add_co_u32 v112, vcc, 0x5000, v112\n\t"
        "v_addc_co_u32 v113, vcc, 0, v113, vcc\n\t"
        "global_load_dwordx4 v[108:111], v[112:113], off\n\t"
        "v_add_co_u32 v112, vcc, 0x5000, v112\n\t"
        "v_addc_co_u32 v113, vcc, 0, v113, vcc\n\t"
        "Ldens%=:\n\t"
        VISIT("v[96:99]")
        VISIT("v[100:103]")
        VISIT("v[104:107]")
        VISIT("v[108:111]")
        "s_sub_u32 %4, %4, 1\n\t"
        "s_cmp_lg_u32 %4, 0\n\t"
        "s_cbranch_scc1 Ldens%=\n\t"
        : "+v"(c0a), "+v"(c0b), "+v"(c1a), "+v"(c1b), "+s"(it)
        : "v"(B0), "v"(B1), "v"(xlo), "v"(xhi), "v"(nha0), "v"(nha1)
        : "vcc", "scc", "memory",
          "v32","v33","v34","v35","v36","v37","v38","v39",
          "v40","v41","v42","v43","v44","v45","v46","v47",
          "v48","v49","v50","v51","v52","v53","v54","v55",
          "v56","v57","v58","v59","v60","v61","v62","v63",
          "v64","v65","v66","v67","v68","v69","v70","v71",
          "v72","v73","v74","v75","v76","v77","v78","v79",
          "v80","v81","v82","v83","v84","v85","v86","v87",
          "v88","v89","v90","v91","v92","v93","v94","v95",
          "v96","v97","v98","v99","v100","v101","v102","v103",
          "v104","v105","v106","v107","v108","v109","v110","v111",
          "v112","v113");

    // per-column count = 32*visits + negatives; combine halves (lanes n, n+32)
    int t0 = c0a + c0b;  t0 += __shfl_xor(t0, 32);
    int t1 = c1a + c1b;  t1 += __shfl_xor(t1, 32);
    const int base = 32 * visits;
    const int g0 = base + t0;
    const int g1 = base + t1;

    __shared__ int red[4][TI];
    if (lane < 32) { red[w][n] = g0; red[w][n + 32] = g1; }
    __syncthreads();
    if (threadIdx.x < TI) {
        const int ii = ibase + threadIdx.x;
        if (ii < N) {
            const int s = red[0][threadIdx.x] + red[1][threadIdx.x] +
                          red[2][threadIdx.x] + red[3][threadIdx.x];
            atomicAdd(&out[ii], s);
        }
    }
}

extern "C" void kernel_launch(void* const* d_in, const int* in_sizes, int n_in,
                              void* d_out, int out_size, void* d_ws, size_t ws_size,
                              hipStream_t stream) {
    const float* pc  = (const float*)d_in[0];   // [N,3] pointcloud
    const float* pad = (const float*)d_in[1];   // [M,3] pointcloud_padding
    int* out = (int*)d_out;

    const int N = in_sizes[0] / 3;              // 20000
    const int M = in_sizes[1] / 3;              // 25000
    const int jt = (M + 31) / 32;               // 782 j-tiles
    int visits = (jt + STREAMS - 1) / STREAMS;  // 20
    visits = (visits + DEPTH - 1) & ~(DEPTH - 1);   // multiple of DEPTH
    const int jtp  = (visits + DEPTH) * STREAMS;    // 960 tiles incl. prefetch overrun
    const int mtot = jtp * 32;                  // 30720 rows (~983 KB in ws)

    dens_pack_kernel<<<(mtot + 255) / 256, 256, 0, stream>>>(
        pad, (uint4*)d_ws, out, M, mtot, N);

    dim3 grid((N + TI - 1) / TI, JS);           // 313 x 10
    dens_mfma_kernel<<<grid, 256, 0, stream>>>(
        pc, (const char*)d_ws, out, N, visits / DEPTH, mtot * 16, visits);
}

// Round 13
// 85.573 us; speedup vs baseline: 1.0154x; 1.0154x over previous
//
#include <hip/hip_runtime.h>

typedef short  bf16x8 __attribute__((ext_vector_type(8)));

#define JS      13           // j-splits (grid.y)
#define STREAMS (JS * 4)     // 52 wave-streams per i-tile (stride in j-tiles)
#define TI      128          // i-points per block (4 MFMA groups per A-load)
#define DEPTH   2            // prefetch depth (buffers X/Y)

__device__ __forceinline__ unsigned short f2bf(float x) {
    unsigned u = __builtin_bit_cast(unsigned, x);
    u += 0x7FFF + ((u >> 16) & 1);          // RNE
    return (unsigned short)(u >> 16);
}
__device__ __forceinline__ float bf2f(unsigned short h) {
    unsigned u = ((unsigned)h) << 16;
    return __builtin_bit_cast(float, u);
}

// ---- pack padding points into MFMA-A planes + zero the output ----
// Row j (K=16 bf16): k0-2 qh | k3-5 ql | k6-8 qh | k9-11 ql | k12-13 negc h/l |
// k14-15 = 1.0,1.0 (pair B's -ha hi/lo threshold fold).
// plane0 = k0-7 (lanes 0-31), plane1 = k8-15 (lanes 32-63).
__global__ __launch_bounds__(256) void dens_pack_kernel(
    const float* __restrict__ pad, uint4* __restrict__ ws,
    int* __restrict__ out, int M, int mtot, int N)
{
    const int j = blockIdx.x * 256 + threadIdx.x;
    if (j < N) out[j] = 0;                      // fold output zeroing here
    if (j >= mtot) return;

    float qx = 0.f, qy = 0.f, qz = 0.f;
    float negc = -1.0e6f;                       // padded rows: s<0 -> sign -1 cancels baseline
    if (j < M) {
        qx = pad[3 * j]; qy = pad[3 * j + 1]; qz = pad[3 * j + 2];
        negc = 0.125f - 0.5f * (qx * qx + qy * qy + qz * qz);   // (r^2 - |q|^2)/2
    }
    const unsigned short xh = f2bf(qx), yh = f2bf(qy), zh = f2bf(qz);
    const unsigned short xl = f2bf(qx - bf2f(xh));
    const unsigned short yl = f2bf(qy - bf2f(yh));
    const unsigned short zl = f2bf(qz - bf2f(zh));
    const unsigned short ch = f2bf(negc);
    const unsigned short cl = f2bf(negc - bf2f(ch));

    uint4 p0, p1;
    p0.x = (unsigned)xh | ((unsigned)yh << 16);   // k0,k1
    p0.y = (unsigned)zh | ((unsigned)xl << 16);   // k2,k3
    p0.z = (unsigned)yl | ((unsigned)zl << 16);   // k4,k5
    p0.w = (unsigned)xh | ((unsigned)yh << 16);   // k6,k7
    p1.x = (unsigned)zh | ((unsigned)xl << 16);   // k8,k9
    p1.y = (unsigned)yl | ((unsigned)zl << 16);   // k10,k11
    p1.z = (unsigned)ch | ((unsigned)cl << 16);   // k12,k13
    p1.w = 0x3F803F80u;                           // k14,k15 = 1.0,1.0
    ws[j]        = p0;                            // plane0
    ws[mtot + j] = p1;                            // plane1
}

// B-frag with threshold folded into k14/k15: s = p.q + negc - ha, within <=> s>=0.
__device__ __forceinline__ void make_bfrag(const float* __restrict__ pc,
                                           int i, int N, int half, bf16x8& B)
{
    float px = 0.f, py = 0.f, pz = 0.f;
    float ha = 3.0e38f;                          // i-pad: s ~ -3e38 < 0 always
    if (i < N) {
        px = pc[3 * i]; py = pc[3 * i + 1]; pz = pc[3 * i + 2];
        ha = 0.5f * (px * px + py * py + pz * pz);   // |p|^2/2, fp32
    }
    const float nha = -ha;
    const unsigned short nhh = f2bf(nha);
    const unsigned short nhl = f2bf(nha - bf2f(nhh));   // 2-term split, err ~1e-5
    const short xh = (short)f2bf(px), yh = (short)f2bf(py), zh = (short)f2bf(pz);
    const short xl = (short)f2bf(px - bf2f((unsigned short)xh));
    const short yl = (short)f2bf(py - bf2f((unsigned short)yh));
    const short zl = (short)f2bf(pz - bf2f((unsigned short)zh));
    const short ONE = (short)0x3F80;
    const bf16x8 Blo = {xh, yh, zh, xh, yh, zh, xl, yl};                    // k0-7
    const bf16x8 Bhi = {zl, xl, yl, zl, ONE, ONE, (short)nhh, (short)nhl};  // k8-15
    B = half ? Bhi : Blo;
}

// consume one 16-elem D group: 16 in-place sign-extracts (full-rate VOP2)
// + 8 v_add3 into two alternating counters. No SGPR-writing VALU (half-rate).
#define CONS(R0,R1,R2,R3,R4,R5,R6,R7,R8,R9,RA,RB,RC,RD,RE,RF, CA, CB) \
    "v_ashrrev_i32 " R0 ", 31, " R0 "\n\t" \
    "v_ashrrev_i32 " R1 ", 31, " R1 "\n\t" \
    "v_ashrrev_i32 " R2 ", 31, " R2 "\n\t" \
    "v_ashrrev_i32 " R3 ", 31, " R3 "\n\t" \
    "v_ashrrev_i32 " R4 ", 31, " R4 "\n\t" \
    "v_ashrrev_i32 " R5 ", 31, " R5 "\n\t" \
    "v_ashrrev_i32 " R6 ", 31, " R6 "\n\t" \
    "v_ashrrev_i32 " R7 ", 31, " R7 "\n\t" \
    "v_ashrrev_i32 " R8 ", 31, " R8 "\n\t" \
    "v_ashrrev_i32 " R9 ", 31, " R9 "\n\t" \
    "v_ashrrev_i32 " RA ", 31, " RA "\n\t" \
    "v_ashrrev_i32 " RB ", 31, " RB "\n\t" \
    "v_ashrrev_i32 " RC ", 31, " RC "\n\t" \
    "v_ashrrev_i32 " RD ", 31, " RD "\n\t" \
    "v_ashrrev_i32 " RE ", 31, " RE "\n\t" \
    "v_ashrrev_i32 " RF ", 31, " RF "\n\t" \
    "v_add3_u32 " CA ", " R0 ", " R1 ", " CA "\n\t" \
    "v_add3_u32 " CB ", " R2 ", " R3 ", " CB "\n\t" \
    "v_add3_u32 " CA ", " R4 ", " R5 ", " CA "\n\t" \
    "v_add3_u32 " CB ", " R6 ", " R7 ", " CB "\n\t" \
    "v_add3_u32 " CA ", " R8 ", " R9 ", " CA "\n\t" \
    "v_add3_u32 " CB ", " RA ", " RB ", " CB "\n\t" \
    "v_add3_u32 " CA ", " RC ", " RD ", " CA "\n\t" \
    "v_add3_u32 " CB ", " RE ", " RF ", " CB "\n\t"

#define CONS_D0(CA, CB) \
    CONS("v32","v33","v34","v35","v36","v37","v38","v39", \
         "v40","v41","v42","v43","v44","v45","v46","v47", CA, CB)
#define CONS_D1(CA, CB) \
    CONS("v48","v49","v50","v51","v52","v53","v54","v55", \
         "v56","v57","v58","v59","v60","v61","v62","v63", CA, CB)

// One visit on A-buffer AR: ONE 1KB wave-load feeds FOUR MFMAs (i-groups 0-3).
// d0/d1 banks alternate; consumes pipeline between MFMAs (in-order WAR-safe).
// AR reload issued only after the last MFMA reads it.
#define VISIT(AR) \
    "s_waitcnt vmcnt(1)\n\t" \
    "v_mfma_f32_32x32x16_bf16 v[32:47], " AR ", %9,  v[64:79]\n\t" \
    "v_mfma_f32_32x32x16_bf16 v[48:63], " AR ", %10, v[64:79]\n\t" \
    "s_nop 7\n\t" \
    "s_nop 2\n\t" \
    CONS_D0("%0", "%1") \
    "v_mfma_f32_32x32x16_bf16 v[32:47], " AR ", %11, v[64:79]\n\t" \
    CONS_D1("%2", "%3") \
    "v_mfma_f32_32x32x16_bf16 v[48:63], " AR ", %12, v[64:79]\n\t" \
    "global_load_dwordx4 " AR ", v[88:89], off\n\t" \
    "v_add_co_u32 v88, vcc, 0x6800, v88\n\t" \
    "v_addc_co_u32 v89, vcc, 0, v89, vcc\n\t" \
    CONS_D0("%4", "%5") \
    CONS_D1("%6", "%7")

// grid (157 x 13), 256 thr. 128-wide i-tile; 52 wave-streams stride j-tiles.
// Physical map: d0=v[32:47] d1=v[48:63] Z=v[64:79] X=v[80:83] Y=v[84:87]
//               addr=v[88:89] (marching, +0x6800/load). 16 visits, 8 iterations.
__global__ __launch_bounds__(256, 4) void dens_mfma_kernel(
    const float* __restrict__ pc,     // [N,3] pointcloud
    const char*  __restrict__ wsA,    // packed A planes ((visits+DEPTH)*STREAMS tiles)
    int* __restrict__ out,            // [N] counts (pre-zeroed)
    int N, int iters, int p1off, int visits)
{
    const int lane = threadIdx.x & 63;
    const int w    = threadIdx.x >> 6;   // wave 0..3
    const int n    = lane & 31;          // output col within 32-tile = i
    const int half = lane >> 5;          // k-chunk 0/1

    const int ibase = blockIdx.x * TI;
    bf16x8 B0, B1, B2, B3;
    make_bfrag(pc, ibase + n,      N, half, B0);
    make_bfrag(pc, ibase + 32 + n, N, half, B1);
    make_bfrag(pc, ibase + 64 + n, N, half, B2);
    make_bfrag(pc, ibase + 96 + n, N, half, B3);

    const int stream = blockIdx.y * 4 + w;          // 0..51
    const unsigned long long ax =
        (unsigned long long)(wsA + (half ? p1off : 0) + n * 16 + (size_t)stream * 512);
    const unsigned xlo = (unsigned)ax, xhi = (unsigned)(ax >> 32);

    int it = iters;
    int c0a = 0, c0b = 0, c1a = 0, c1b = 0, c2a = 0, c2b = 0, c3a = 0, c3b = 0;

    asm volatile(
        // ---- preamble: marching addr, Z=0 bank, DEPTH prefetches ----
        "v_mov_b32 v88, %13\n\t"
        "v_mov_b32 v89, %14\n\t"
        "v_mov_b32 v64, 0\n\t" "v_mov_b32 v65, 0\n\t"
        "v_mov_b32 v66, 0\n\t" "v_mov_b32 v67, 0\n\t"
        "v_mov_b32 v68, 0\n\t" "v_mov_b32 v69, 0\n\t"
        "v_mov_b32 v70, 0\n\t" "v_mov_b32 v71, 0\n\t"
        "v_mov_b32 v72, 0\n\t" "v_mov_b32 v73, 0\n\t"
        "v_mov_b32 v74, 0\n\t" "v_mov_b32 v75, 0\n\t"
        "v_mov_b32 v76, 0\n\t" "v_mov_b32 v77, 0\n\t"
        "v_mov_b32 v78, 0\n\t" "v_mov_b32 v79, 0\n\t"
        "global_load_dwordx4 v[80:83], v[88:89], off\n\t"
        "v_add_co_u32 v88, vcc, 0x6800, v88\n\t"
        "v_addc_co_u32 v89, vcc, 0, v89, vcc\n\t"
        "global_load_dwordx4 v[84:87], v[88:89], off\n\t"
        "v_add_co_u32 v88, vcc, 0x6800, v88\n\t"
        "v_addc_co_u32 v89, vcc, 0, v89, vcc\n\t"
        "Ldens%=:\n\t"
        VISIT("v[80:83]")
        VISIT("v[84:87]")
        "s_sub_u32 %8, %8, 1\n\t"
        "s_cmp_lg_u32 %8, 0\n\t"
        "s_cbranch_scc1 Ldens%=\n\t"
        : "+v"(c0a), "+v"(c0b), "+v"(c1a), "+v"(c1b),
          "+v"(c2a), "+v"(c2b), "+v"(c3a), "+v"(c3b), "+s"(it)
        : "v"(B0), "v"(B1), "v"(B2), "v"(B3), "v"(xlo), "v"(xhi)
        : "vcc", "scc", "memory",
          "v32","v33","v34","v35","v36","v37","v38","v39",
          "v40","v41","v42","v43","v44","v45","v46","v47",
          "v48","v49","v50","v51","v52","v53","v54","v55",
          "v56","v57","v58","v59","v60","v61","v62","v63",
          "v64","v65","v66","v67","v68","v69","v70","v71",
          "v72","v73","v74","v75","v76","v77","v78","v79",
          "v80","v81","v82","v83","v84","v85","v86","v87",
          "v88","v89");

    // per-column count = 32*visits + sign-sums; combine halves (lanes n, n+32)
    const int base = 32 * visits;
    int t0 = c0a + c0b;  t0 += __shfl_xor(t0, 32);
    int t1 = c1a + c1b;  t1 += __shfl_xor(t1, 32);
    int t2 = c2a + c2b;  t2 += __shfl_xor(t2, 32);
    int t3 = c3a + c3b;  t3 += __shfl_xor(t3, 32);

    __shared__ int red[4][TI];
    if (lane < 32) {
        red[w][n]      = base + t0;
        red[w][n + 32] = base + t1;
        red[w][n + 64] = base + t2;
        red[w][n + 96] = base + t3;
    }
    __syncthreads();
    if (threadIdx.x < TI) {
        const int ii = ibase + threadIdx.x;
        if (ii < N) {
            const int s = red[0][threadIdx.x] + red[1][threadIdx.x] +
                          red[2][threadIdx.x] + red[3][threadIdx.x];
            atomicAdd(&out[ii], s);
        }
    }
}

extern "C" void kernel_launch(void* const* d_in, const int* in_sizes, int n_in,
                              void* d_out, int out_size, void* d_ws, size_t ws_size,
                              hipStream_t stream) {
    const float* pc  = (const float*)d_in[0];   // [N,3] pointcloud
    const float* pad = (const float*)d_in[1];   // [M,3] pointcloud_padding
    int* out = (int*)d_out;

    const int N = in_sizes[0] / 3;              // 20000
    const int M = in_sizes[1] / 3;              // 25000
    const int jt = (M + 31) / 32;               // 782 j-tiles
    int visits = (jt + STREAMS - 1) / STREAMS;  // 16
    if (visits & 1) visits++;                   // 2-visit unrolled body
    const int jtp  = (visits + DEPTH) * STREAMS;    // 936 tiles incl. prefetch overrun
    const int mtot = jtp * 32;                  // 29952 rows (~958 KB in ws)

    dens_pack_kernel<<<(mtot + 255) / 256, 256, 0, stream>>>(
        pad, (uint4*)d_ws, out, M, mtot, N);

    dim3 grid((N + TI - 1) / TI, JS);           // 157 x 13
    dens_mfma_kernel<<<grid, 256, 0, stream>>>(
        pc, (const char*)d_ws, out, N, visits / 2, mtot * 16, visits);
}